// Round 9
// baseline (164.826 us; speedup 1.0000x reference)
//
#include <hip/hip_runtime.h>
#include <hip/hip_bf16.h>
#include <math.h>

// Problem constants (B=2, S=2048, C=1024, H=16, D=64, Cv=1024)
#define B_    2
#define S_    2048
#define C_    1024
#define H_    16
#define D_    64
#define TWO_C 2048
#define CV    1024
#define K_    1024
#define N_ALL 3072   // Wqk (2048) ++ Wv (1024)

typedef float  floatx4  __attribute__((ext_vector_type(4)));
typedef float  floatx16 __attribute__((ext_vector_type(16)));
typedef short  shortx8  __attribute__((ext_vector_type(8)));
typedef short  shortx4  __attribute__((ext_vector_type(4)));

__device__ __forceinline__ ushort f2bf(float f) {
  unsigned u = __builtin_bit_cast(unsigned, f);
  u += 0x7fff + ((u >> 16) & 1);   // RNE
  return (ushort)(u >> 16);
}

// async global->LDS, 16B per lane; LDS dst = wave-uniform base + lane*16
__device__ __forceinline__ void gl2lds16(const ushort* g, ushort* l) {
  __builtin_amdgcn_global_load_lds(
      (const __attribute__((address_space(1))) unsigned int*)(const void*)g,
      (__attribute__((address_space(3))) unsigned int*)(void*)l, 16, 0, 0);
}

// ---------------- prep v2 (unchanged R8): 1024 fat blocks ------------------
__global__ __launch_bounds__(256) void prep_kernel(
    const float* __restrict__ x, const float* __restrict__ Wqk,
    const float* __restrict__ Wv, ushort* __restrict__ xbf,
    ushort* __restrict__ wtbf) {
  const int blk = blockIdx.x;
  if (blk < 256) {
    const int stride = 256 * 256;
    for (int i = blk * 256 + threadIdx.x; i < (B_ * S_ * C_) / 4; i += stride) {
      float4 v = *(const float4*)(x + (size_t)i * 4);
      shortx4 s;
      s[0] = (short)f2bf(v.x); s[1] = (short)f2bf(v.y);
      s[2] = (short)f2bf(v.z); s[3] = (short)f2bf(v.w);
      *(shortx4*)(xbf + (size_t)i * 4) = s;
    }
    return;
  }
  __shared__ ushort tile[64][65];
  int idx = blk - 256;
  const float* W; ushort* WT; int N;
  if (idx < 512) { W = Wqk; WT = wtbf; N = TWO_C; }
  else { idx -= 512; W = Wv; WT = wtbf + (size_t)TWO_C * K_; N = CV; }
  const int nb = N / 64;
  const int n0 = (idx % nb) * 64, k0 = (idx / nb) * 64;
  const int tc = threadIdx.x & 63, tr = threadIdx.x >> 6;
#pragma unroll
  for (int i = 0; i < 64; i += 4)
    tile[tc][tr + i] = f2bf(W[(size_t)(k0 + tr + i) * N + n0 + tc]);
  __syncthreads();
  const int n = threadIdx.x >> 2, ch = threadIdx.x & 3;
  shortx8 s0, s1;
#pragma unroll
  for (int j = 0; j < 8; j++) { s0[j] = tile[n][ch * 16 + j]; s1[j] = tile[n][ch * 16 + 8 + j]; }
  ushort* dst = WT + (size_t)(n0 + n) * K_ + k0 + ch * 16;
  *(shortx8*)(dst) = s0;
  *(shortx8*)(dst + 8) = s1;
}

// ---------------- fused projection GEMM (unchanged R8: known-good ~48us) ---
__global__ __launch_bounds__(256) void gemm_mfma(
    const ushort* __restrict__ A, const ushort* __restrict__ BT,
    const float* __restrict__ bqk, const float* __restrict__ bv,
    ushort* __restrict__ qkout, ushort* __restrict__ vtout) {
  __shared__ __align__(16) ushort As[128 * 64];   // 16 KB
  __shared__ __align__(16) ushort Bs[128 * 64];   // 16 KB

  const int tx = threadIdx.x;
  const int w = tx >> 6;
  const int lane = tx & 63;
  const int lq = lane & 15;
  const int quad = lane >> 4;
  const int row0 = blockIdx.x * 128;   // row fastest (XCD round-robin shares B)
  const int col0 = blockIdx.y * 128;
  const int wm = (w & 1) * 64;
  const int wn = (w >> 1) * 64;

  const int srow = lane >> 3;
  const int schunk = ((lane & 7) ^ srow) * 8;
  const ushort* ag = A  + (size_t)(row0 + srow) * K_ + schunk;
  const ushort* bg = BT + (size_t)(col0 + srow) * K_ + schunk;

  floatx4 acc[4][4];
#pragma unroll
  for (int i = 0; i < 4; i++)
#pragma unroll
    for (int j = 0; j < 4; j++) acc[i][j] = (floatx4){0.f, 0.f, 0.f, 0.f};

  for (int k0 = 0; k0 < K_; k0 += 64) {
#pragma unroll
    for (int j = 0; j < 4; j++) {
      const int g = w * 4 + j;
      gl2lds16(ag + (size_t)(g * 8) * K_ + k0, As + g * 512);
      gl2lds16(bg + (size_t)(g * 8) * K_ + k0, Bs + g * 512);
    }
    __syncthreads();

#pragma unroll
    for (int kh = 0; kh < 2; kh++) {
      const int co = ((kh * 4 + quad) ^ (lq & 7)) * 8;
      shortx8 af[4], bf[4];
#pragma unroll
      for (int mi = 0; mi < 4; mi++)
        af[mi] = *(const shortx8*)(As + (wm + mi * 16 + lq) * 64 + co);
#pragma unroll
      for (int ni = 0; ni < 4; ni++)
        bf[ni] = *(const shortx8*)(Bs + (wn + ni * 16 + lq) * 64 + co);
#pragma unroll
      for (int mi = 0; mi < 4; mi++)
#pragma unroll
        for (int ni = 0; ni < 4; ni++)
          acc[mi][ni] = __builtin_amdgcn_mfma_f32_16x16x32_bf16(
              af[mi], bf[ni], acc[mi][ni], 0, 0, 0);
    }
    __syncthreads();
  }

  if (col0 < TWO_C) {
#pragma unroll
    for (int mi = 0; mi < 4; mi++) {
      const int m0 = row0 + wm + mi * 16 + quad * 4;
#pragma unroll
      for (int ni = 0; ni < 4; ni++) {
        const int n = col0 + wn + ni * 16 + lq;
        const float bs = bqk[n];
        const float sc = (n < C_) ? 0.125f : 1.0f;
#pragma unroll
        for (int r = 0; r < 4; r++)
          qkout[(size_t)(m0 + r) * TWO_C + n] = f2bf((acc[mi][ni][r] + bs) * sc);
      }
    }
  } else {
#pragma unroll
    for (int mi = 0; mi < 4; mi++) {
      const int m0 = row0 + wm + mi * 16 + quad * 4;
      const int b = m0 >> 11, s = m0 & (S_ - 1);
#pragma unroll
      for (int ni = 0; ni < 4; ni++) {
        const int n = col0 - TWO_C + wn + ni * 16 + lq;
        const float bs = bv[n];
        shortx4 st;
#pragma unroll
        for (int r = 0; r < 4; r++) st[r] = (short)f2bf(acc[mi][ni][r] + bs);
        *(shortx4*)(vtout + ((size_t)((b << 4) | (n >> 6)) * 64 + (n & 63)) * S_ + s) = st;
      }
    }
  }
}

// ---------------- Flash attention v4: 32x32x16 MFMA, paired k-split --------
// Block = 64 q (waves 0,1 -> q 0..31 / waves 2,3 -> q 32..63), wave kh = w&1
// owns 32 of the 64 keys per k-tile. Per wave-iter LDS reads: K 4 KB + V 4 KB
// + P 2 KB (vs 18 KB in v3) -> total traffic -33%. P is wave-private (no
// S->O barrier). Cross-wave O/l reduction once per block via LDS.
// 32x32 C-layout (m74/m101): col = lane&31, row = (reg&3)+8*(reg>>2)+4*(lane>>5).
__global__ __launch_bounds__(256, 4) void flash_attn(
    const ushort* __restrict__ qk, const ushort* __restrict__ vt,
    float* __restrict__ out) {
  __shared__ __align__(16) char smem[25088];
  ushort* Ks = (ushort*)smem;            // 8 KB [64 key][64 d], XOR-octet swz
  ushort* Vs = (ushort*)(smem + 8192);   // 8 KB [64 d][64 key], XOR-octet swz
  ushort* Ps = (ushort*)(smem + 16384);  // 8 KB: 4 x [32 q][32 key], XOR-quad swz
  float*  Ls = (float*)(smem + 24576);   // 512 B: per-wave l[q]
  float*  red = (float*)smem;            // epilogue O-reduction (reuses K/V/P)

  const int tx = threadIdx.x;
  const int w = tx >> 6, lane = tx & 63;
  const int col = lane & 31, hw = lane >> 5;
  const int kh = w & 1, qh = w >> 1;

  const int bh = blockIdx.x & 31;
  const int qtile = 31 - (blockIdx.x >> 5);  // heavy tiles first
  const int b = bh >> 4, h = bh & 15;
  const int q0 = qtile * 64;
  const int qg = q0 + qh * 32 + col;         // this lane's query (cols of S^T)

  // Q B-frags (pre-scaled 1/8): n = col (q), k = d = s*16 + hw*8 + j
  const ushort* qb = qk + (size_t)(b * S_ + qg) * TWO_C + h * D_;
  shortx8 qf[4];
#pragma unroll
  for (int s = 0; s < 4; s++) qf[s] = *(const shortx8*)(qb + s * 16 + hw * 8);

  const ushort* kbase = qk + (size_t)b * S_ * TWO_C + C_ + h * D_;
  const ushort* vbase = vt + (size_t)(b * H_ + h) * D_ * S_;
  const int kk = lane >> 3, oo = lane & 7;
  const int oswz = (oo ^ kk) * 8;
  const ushort* ksrc = kbase + (size_t)(w * 16 + kk) * TWO_C + oswz;
  const ushort* vsrc = vbase + (size_t)(w * 16 + kk) * S_ + oswz;

  floatx16 o0, o1;
#pragma unroll
  for (int r = 0; r < 16; r++) { o0[r] = 0.f; o1[r] = 0.f; }
  float l = 0.f;
  ushort* Pw = Ps + w * 1024;
  const int krow = kh * 32 + col;       // K A-frag row (this lane's key)
  const int vrow0 = col, vrow1 = 32 + col;

  const int nkt = qtile + 1;
  for (int t = 0; t < nkt; t++) {
    const size_t k0 = (size_t)t * 64;
    gl2lds16(ksrc + k0 * TWO_C,             Ks + (2 * w) * 512);
    gl2lds16(ksrc + k0 * TWO_C + 8 * TWO_C, Ks + (2 * w + 1) * 512);
    gl2lds16(vsrc + k0,                     Vs + (2 * w) * 512);
    gl2lds16(vsrc + k0 + 8 * S_,            Vs + (2 * w + 1) * 512);
    __syncthreads();   // DMA drained; previous compute done

    // S^T[32 key (kh half)][32 q] = K_half . Q^T, accumulate over d (4 slices)
    floatx16 sa;
#pragma unroll
    for (int r = 0; r < 16; r++) sa[r] = 0.f;
#pragma unroll
    for (int s = 0; s < 4; s++) {
      const shortx8 kf = *(const shortx8*)(
          Ks + krow * 64 + (((2 * s + hw) ^ (krow & 7)) << 3));
      sa = __builtin_amdgcn_mfma_f32_32x32x16_bf16(kf, qf[s], sa, 0, 0, 0);
    }

    if (t == qtile) {  // causal boundary: mask key > q (wave kh=1,qh=0: all)
#pragma unroll
      for (int r = 0; r < 16; r++) {
        const int key_loc = kh * 32 + (r & 3) + ((r >> 2) << 3) + hw * 4;
        if (key_loc > qh * 32 + col) sa[r] = -1e30f;
      }
    }

    // softmax (fixed m=0), pack P^T stripe (wave-private) to LDS
    float psum = 0.f;
#pragma unroll
    for (int g = 0; g < 4; g++) {
      shortx4 pw;
#pragma unroll
      for (int r = 0; r < 4; r++) {
        const float p = __expf(sa[g * 4 + r]);
        psum += p;
        pw[r] = (short)f2bf(p);
      }
      // keys g*8 + hw*4 + 0..3 at row q=col; octet g at physical g^(col&3)
      *(shortx4*)(Pw + col * 32 + ((g ^ (col & 3)) << 3) + hw * 4) = pw;
    }
    l += psum;
    __asm__ __volatile__("s_waitcnt lgkmcnt(0)" ::: "memory");

    // P^T B-frags: n = col (q), k = key = s2*16 + hw*8 + j (local to kh half)
    const shortx8 pf0 = *(const shortx8*)(Pw + col * 32 + ((hw ^ (col & 3)) << 3));
    const shortx8 pf1 = *(const shortx8*)(Pw + col * 32 + (((2 + hw) ^ (col & 3)) << 3));

    // O^T += V^T . P^T over this wave's 32 keys
#pragma unroll
    for (int s2 = 0; s2 < 2; s2++) {
      const shortx8 pf = s2 ? pf1 : pf0;
      const int kc = 4 * kh + 2 * s2 + hw;   // key chunk in V rows
      const shortx8 vf0 = *(const shortx8*)(
          Vs + vrow0 * 64 + ((kc ^ (vrow0 & 7)) << 3));
      const shortx8 vf1 = *(const shortx8*)(
          Vs + vrow1 * 64 + ((kc ^ (vrow1 & 7)) << 3));
      o0 = __builtin_amdgcn_mfma_f32_32x32x16_bf16(vf0, pf, o0, 0, 0, 0);
      o1 = __builtin_amdgcn_mfma_f32_32x32x16_bf16(vf1, pf, o1, 0, 0, 0);
    }
    __syncthreads();   // K/V/P consumed; safe to restage
  }

  // l: add hw partner (other 16 keys of this wave's half)
  l += __shfl_xor(l, 32, 64);
  Ls[w * 32 + col] = l;

  // O reduction across the kh pair: odd wave -> LDS, even wave adds
  float* myred = red + (w >> 1) * 2112;
  if (kh == 1) {
#pragma unroll
    for (int r = 0; r < 16; r++) {
      myred[lane * 33 + r]      = o0[r];
      myred[lane * 33 + 16 + r] = o1[r];
    }
  }
  __syncthreads();
  if (kh == 0) {
    const float inv = 1.0f / (Ls[w * 32 + col] + Ls[(w + 1) * 32 + col]);
#pragma unroll
    for (int r = 0; r < 16; r++) {
      o0[r] = (o0[r] + myred[lane * 33 + r]) * inv;
      o1[r] = (o1[r] + myred[lane * 33 + 16 + r]) * inv;
    }
    // store: regs 4g..4g+3 are 4 consecutive d at base sub*32 + 8g + 4hw
    float* op = out + (size_t)(b * S_ + qg) * CV + h * D_;
#pragma unroll
    for (int g = 0; g < 4; g++) {
      floatx4 v0, v1;
#pragma unroll
      for (int j = 0; j < 4; j++) { v0[j] = o0[g * 4 + j]; v1[j] = o1[g * 4 + j]; }
      *(floatx4*)(op + g * 8 + hw * 4)      = v0;
      *(floatx4*)(op + 32 + g * 8 + hw * 4) = v1;
    }
  }
}

extern "C" void kernel_launch(void* const* d_in, const int* in_sizes, int n_in,
                              void* d_out, int out_size, void* d_ws, size_t ws_size,
                              hipStream_t stream) {
  const float* x   = (const float*)d_in[0];
  const float* Wqk = (const float*)d_in[1];
  const float* bqk = (const float*)d_in[2];
  const float* Wv  = (const float*)d_in[3];
  const float* bv  = (const float*)d_in[4];
  float* out = (float*)d_out;

  // Workspace (ushorts): qk [4096][2048] | V^T [2048][2048] | xbf [4096][1024]
  //                      | wtbf [3072][1024]   => ~39.8 MB total
  ushort* qkbf = (ushort*)d_ws;
  ushort* vtbf = qkbf + (size_t)(B_ * S_) * TWO_C;
  ushort* xbf  = vtbf + (size_t)TWO_C * S_;
  ushort* wtbf = xbf  + (size_t)(B_ * S_) * K_;

  dim3 blk(256);
  prep_kernel<<<dim3(1024), blk, 0, stream>>>(x, Wqk, Wv, xbf, wtbf);
  gemm_mfma<<<dim3((B_ * S_) / 128, N_ALL / 128), blk, 0, stream>>>(
      xbf, wtbf, bqk, bv, qkbf, vtbf);
  flash_attn<<<dim3(32 * 32), blk, 0, stream>>>(qkbf, vtbf, out);
}

// Round 10
// 158.796 us; speedup vs baseline: 1.0380x; 1.0380x over previous
//
#include <hip/hip_runtime.h>
#include <hip/hip_bf16.h>
#include <math.h>

// Problem constants (B=2, S=2048, C=1024, H=16, D=64, Cv=1024)
#define B_    2
#define S_    2048
#define C_    1024
#define H_    16
#define D_    64
#define TWO_C 2048
#define CV    1024
#define K_    1024
#define N_ALL 3072   // Wqk (2048) ++ Wv (1024)

typedef float  floatx4  __attribute__((ext_vector_type(4)));
typedef float  floatx16 __attribute__((ext_vector_type(16)));
typedef short  shortx8  __attribute__((ext_vector_type(8)));
typedef short  shortx4  __attribute__((ext_vector_type(4)));

__device__ __forceinline__ ushort f2bf(float f) {
  unsigned u = __builtin_bit_cast(unsigned, f);
  u += 0x7fff + ((u >> 16) & 1);   // RNE
  return (ushort)(u >> 16);
}

// async global->LDS, 16B per lane; LDS dst = wave-uniform base + lane*16
__device__ __forceinline__ void gl2lds16(const ushort* g, ushort* l) {
  __builtin_amdgcn_global_load_lds(
      (const __attribute__((address_space(1))) unsigned int*)(const void*)g,
      (__attribute__((address_space(3))) unsigned int*)(void*)l, 16, 0, 0);
}

// ---------------- prep v2 (unchanged): 1024 fat blocks ---------------------
__global__ __launch_bounds__(256) void prep_kernel(
    const float* __restrict__ x, const float* __restrict__ Wqk,
    const float* __restrict__ Wv, ushort* __restrict__ xbf,
    ushort* __restrict__ wtbf) {
  const int blk = blockIdx.x;
  if (blk < 256) {
    const int stride = 256 * 256;
    for (int i = blk * 256 + threadIdx.x; i < (B_ * S_ * C_) / 4; i += stride) {
      float4 v = *(const float4*)(x + (size_t)i * 4);
      shortx4 s;
      s[0] = (short)f2bf(v.x); s[1] = (short)f2bf(v.y);
      s[2] = (short)f2bf(v.z); s[3] = (short)f2bf(v.w);
      *(shortx4*)(xbf + (size_t)i * 4) = s;
    }
    return;
  }
  __shared__ ushort tile[64][65];
  int idx = blk - 256;
  const float* W; ushort* WT; int N;
  if (idx < 512) { W = Wqk; WT = wtbf; N = TWO_C; }
  else { idx -= 512; W = Wv; WT = wtbf + (size_t)TWO_C * K_; N = CV; }
  const int nb = N / 64;
  const int n0 = (idx % nb) * 64, k0 = (idx / nb) * 64;
  const int tc = threadIdx.x & 63, tr = threadIdx.x >> 6;
#pragma unroll
  for (int i = 0; i < 64; i += 4)
    tile[tc][tr + i] = f2bf(W[(size_t)(k0 + tr + i) * N + n0 + tc]);
  __syncthreads();
  const int n = threadIdx.x >> 2, ch = threadIdx.x & 3;
  shortx8 s0, s1;
#pragma unroll
  for (int j = 0; j < 8; j++) { s0[j] = tile[n][ch * 16 + j]; s1[j] = tile[n][ch * 16 + 8 + j]; }
  ushort* dst = WT + (size_t)(n0 + n) * K_ + k0 + ch * 16;
  *(shortx8*)(dst) = s0;
  *(shortx8*)(dst + 8) = s1;
}

// ---------------- fused projection GEMM (unchanged: known-good ~47us) ------
__global__ __launch_bounds__(256) void gemm_mfma(
    const ushort* __restrict__ A, const ushort* __restrict__ BT,
    const float* __restrict__ bqk, const float* __restrict__ bv,
    ushort* __restrict__ qkout, ushort* __restrict__ vtout) {
  __shared__ __align__(16) ushort As[128 * 64];   // 16 KB
  __shared__ __align__(16) ushort Bs[128 * 64];   // 16 KB

  const int tx = threadIdx.x;
  const int w = tx >> 6;
  const int lane = tx & 63;
  const int lq = lane & 15;
  const int quad = lane >> 4;
  const int row0 = blockIdx.x * 128;   // row fastest (XCD round-robin shares B)
  const int col0 = blockIdx.y * 128;
  const int wm = (w & 1) * 64;
  const int wn = (w >> 1) * 64;

  const int srow = lane >> 3;
  const int schunk = ((lane & 7) ^ srow) * 8;
  const ushort* ag = A  + (size_t)(row0 + srow) * K_ + schunk;
  const ushort* bg = BT + (size_t)(col0 + srow) * K_ + schunk;

  floatx4 acc[4][4];
#pragma unroll
  for (int i = 0; i < 4; i++)
#pragma unroll
    for (int j = 0; j < 4; j++) acc[i][j] = (floatx4){0.f, 0.f, 0.f, 0.f};

  for (int k0 = 0; k0 < K_; k0 += 64) {
#pragma unroll
    for (int j = 0; j < 4; j++) {
      const int g = w * 4 + j;
      gl2lds16(ag + (size_t)(g * 8) * K_ + k0, As + g * 512);
      gl2lds16(bg + (size_t)(g * 8) * K_ + k0, Bs + g * 512);
    }
    __syncthreads();

#pragma unroll
    for (int kh = 0; kh < 2; kh++) {
      const int co = ((kh * 4 + quad) ^ (lq & 7)) * 8;
      shortx8 af[4], bf[4];
#pragma unroll
      for (int mi = 0; mi < 4; mi++)
        af[mi] = *(const shortx8*)(As + (wm + mi * 16 + lq) * 64 + co);
#pragma unroll
      for (int ni = 0; ni < 4; ni++)
        bf[ni] = *(const shortx8*)(Bs + (wn + ni * 16 + lq) * 64 + co);
#pragma unroll
      for (int mi = 0; mi < 4; mi++)
#pragma unroll
        for (int ni = 0; ni < 4; ni++)
          acc[mi][ni] = __builtin_amdgcn_mfma_f32_16x16x32_bf16(
              af[mi], bf[ni], acc[mi][ni], 0, 0, 0);
    }
    __syncthreads();
  }

  if (col0 < TWO_C) {
#pragma unroll
    for (int mi = 0; mi < 4; mi++) {
      const int m0 = row0 + wm + mi * 16 + quad * 4;
#pragma unroll
      for (int ni = 0; ni < 4; ni++) {
        const int n = col0 + wn + ni * 16 + lq;
        const float bs = bqk[n];
        const float sc = (n < C_) ? 0.125f : 1.0f;
#pragma unroll
        for (int r = 0; r < 4; r++)
          qkout[(size_t)(m0 + r) * TWO_C + n] = f2bf((acc[mi][ni][r] + bs) * sc);
      }
    }
  } else {
#pragma unroll
    for (int mi = 0; mi < 4; mi++) {
      const int m0 = row0 + wm + mi * 16 + quad * 4;
      const int b = m0 >> 11, s = m0 & (S_ - 1);
#pragma unroll
      for (int ni = 0; ni < 4; ni++) {
        const int n = col0 - TWO_C + wn + ni * 16 + lq;
        const float bs = bv[n];
        shortx4 st;
#pragma unroll
        for (int r = 0; r < 4; r++) st[r] = (short)f2bf(acc[mi][ni][r] + bs);
        *(shortx4*)(vtout + ((size_t)((b << 4) | (n >> 6)) * 64 + (n & 63)) * S_ + s) = st;
      }
    }
  }
}

// ---------------- Flash attention v5: 32x32 tiling + fixed P swizzle + dbuf
// Block = 64 q (waves 0,1 -> q 0..31 / 2,3 -> q 32..63); wave kh = w&1 owns 32
// of 64 keys. LDS: Ks 2x8KB | Vs 2x8KB | Ps 8KB = 40960 B -> 4 blocks/CU.
// P rows are 64 B (32 ushorts): bank index gets 16*(col&1) from the row, so
// the swizzle key is (col>>1)&3 (the two bank-relevant row bits). Verified
// vs the 8-lane/phase (b128) and 16-lane/phase (b64) conflict model:
// writes 2-way (free, m136), reads conflict-free.
// K/V double-buffered: DMA(t+1) issued right after the barrier that drains
// DMA(t), so DMA latency overlaps compute(t).
__global__ __launch_bounds__(256, 4) void flash_attn(
    const ushort* __restrict__ qk, const ushort* __restrict__ vt,
    float* __restrict__ out) {
  __shared__ __align__(16) char smem[40960];
  ushort* KsB = (ushort*)smem;             // 2 x [64 key][64 d], XOR-octet swz
  ushort* VsB = (ushort*)(smem + 16384);   // 2 x [64 d][64 key], XOR-octet swz
  ushort* Ps  = (ushort*)(smem + 32768);   // 4 waves x [32 q][32 key]
  float*  Ls  = (float*)(smem + 40448);    // 512 B (Ps tail, used post-loop)
  float*  red = (float*)smem;              // epilogue O-reduction (reuses K/V)

  const int tx = threadIdx.x;
  const int w = tx >> 6, lane = tx & 63;
  const int col = lane & 31, hw = lane >> 5;
  const int kh = w & 1, qh = w >> 1;
  const int sw2 = (col >> 1) & 3;          // P swizzle key

  const int bh = blockIdx.x & 31;
  const int qtile = 31 - (blockIdx.x >> 5);  // heavy tiles first
  const int b = bh >> 4, h = bh & 15;
  const int q0 = qtile * 64;
  const int qg = q0 + qh * 32 + col;         // this lane's query

  // Q B-frags (pre-scaled 1/8): n = col (q), k = d = s*16 + hw*8 + j
  const ushort* qb = qk + (size_t)(b * S_ + qg) * TWO_C + h * D_;
  shortx8 qf[4];
#pragma unroll
  for (int s = 0; s < 4; s++) qf[s] = *(const shortx8*)(qb + s * 16 + hw * 8);

  const ushort* kbase = qk + (size_t)b * S_ * TWO_C + C_ + h * D_;
  const ushort* vbase = vt + (size_t)(b * H_ + h) * D_ * S_;
  const int kk = lane >> 3, oo = lane & 7;
  const int oswz = (oo ^ kk) * 8;
  const ushort* ksrc = kbase + (size_t)(w * 16 + kk) * TWO_C + oswz;
  const ushort* vsrc = vbase + (size_t)(w * 16 + kk) * S_ + oswz;

  floatx16 o0, o1;
#pragma unroll
  for (int r = 0; r < 16; r++) { o0[r] = 0.f; o1[r] = 0.f; }
  float l = 0.f;
  ushort* Pw = Ps + w * 1024;
  const int krow = kh * 32 + col;       // K A-frag row (this lane's key)
  const int vrow0 = col, vrow1 = 32 + col;

  const int nkt = qtile + 1;

  // preload tile 0 into buffer 0
  gl2lds16(ksrc,             KsB + (2 * w) * 512);
  gl2lds16(ksrc + 8 * TWO_C, KsB + (2 * w + 1) * 512);
  gl2lds16(vsrc,             VsB + (2 * w) * 512);
  gl2lds16(vsrc + 8 * S_,    VsB + (2 * w + 1) * 512);

  for (int t = 0; t < nkt; t++) {
    const int buf = t & 1;
    __syncthreads();   // drains DMA(t) via vmcnt; all compute(t-1) done

    if (t + 1 < nkt) {
      const size_t k1 = (size_t)(t + 1) * 64;
      ushort* kd = KsB + (buf ^ 1) * 4096;
      ushort* vd = VsB + (buf ^ 1) * 4096;
      gl2lds16(ksrc + k1 * TWO_C,             kd + (2 * w) * 512);
      gl2lds16(ksrc + k1 * TWO_C + 8 * TWO_C, kd + (2 * w + 1) * 512);
      gl2lds16(vsrc + k1,                     vd + (2 * w) * 512);
      gl2lds16(vsrc + k1 + 8 * S_,            vd + (2 * w + 1) * 512);
    }

    const ushort* Kb = KsB + buf * 4096;
    const ushort* Vb = VsB + buf * 4096;

    // S^T[32 key (kh half)][32 q] = K_half . Q^T over d (4 slices of 16)
    floatx16 sa;
#pragma unroll
    for (int r = 0; r < 16; r++) sa[r] = 0.f;
#pragma unroll
    for (int s = 0; s < 4; s++) {
      const shortx8 kf = *(const shortx8*)(
          Kb + krow * 64 + (((2 * s + hw) ^ (krow & 7)) << 3));
      sa = __builtin_amdgcn_mfma_f32_32x32x16_bf16(kf, qf[s], sa, 0, 0, 0);
    }

    if (t == qtile) {  // causal boundary: mask key > q
#pragma unroll
      for (int r = 0; r < 16; r++) {
        const int key_loc = kh * 32 + (r & 3) + ((r >> 2) << 3) + hw * 4;
        if (key_loc > qh * 32 + col) sa[r] = -1e30f;
      }
    }

    // softmax (fixed m=0), pack wave-private P^T stripe to LDS
    float psum = 0.f;
#pragma unroll
    for (int g = 0; g < 4; g++) {
      shortx4 pw;
#pragma unroll
      for (int r = 0; r < 4; r++) {
        const float p = __expf(sa[g * 4 + r]);
        psum += p;
        pw[r] = (short)f2bf(p);
      }
      // keys g*8 + hw*4 + 0..3 at row q=col; chunk16 g at physical g^sw2
      *(shortx4*)(Pw + col * 32 + ((g ^ sw2) << 3) + hw * 4) = pw;
    }
    l += psum;
    __asm__ __volatile__("s_waitcnt lgkmcnt(0)" ::: "memory");

    // P^T B-frags: n = col (q), local key = s2*16 + hw*8 + j -> chunk s2*2+hw
    const shortx8 pf0 = *(const shortx8*)(Pw + col * 32 + ((hw ^ sw2) << 3));
    const shortx8 pf1 = *(const shortx8*)(Pw + col * 32 + (((2 + hw) ^ sw2) << 3));

    // O^T += V^T . P^T over this wave's 32 keys
#pragma unroll
    for (int s2 = 0; s2 < 2; s2++) {
      const shortx8 pf = s2 ? pf1 : pf0;
      const int kc = 4 * kh + 2 * s2 + hw;   // key chunk in V rows
      const shortx8 vf0 = *(const shortx8*)(
          Vb + vrow0 * 64 + ((kc ^ (vrow0 & 7)) << 3));
      const shortx8 vf1 = *(const shortx8*)(
          Vb + vrow1 * 64 + ((kc ^ (vrow1 & 7)) << 3));
      o0 = __builtin_amdgcn_mfma_f32_32x32x16_bf16(vf0, pf, o0, 0, 0, 0);
      o1 = __builtin_amdgcn_mfma_f32_32x32x16_bf16(vf1, pf, o1, 0, 0, 0);
    }
  }
  __syncthreads();   // all compute done; K/V/P regions reusable

  // l: add hw partner (other 16 keys of this wave's half), publish per wave
  l += __shfl_xor(l, 32, 64);
  Ls[w * 32 + col] = l;

  // O reduction across the kh pair: odd wave -> LDS, even wave adds
  float* myred = red + qh * 2112;
  if (kh == 1) {
#pragma unroll
    for (int r = 0; r < 16; r++) {
      myred[lane * 33 + r]      = o0[r];
      myred[lane * 33 + 16 + r] = o1[r];
    }
  }
  __syncthreads();
  if (kh == 0) {
    const float inv = 1.0f / (Ls[w * 32 + col] + Ls[(w + 1) * 32 + col]);
#pragma unroll
    for (int r = 0; r < 16; r++) {
      o0[r] = (o0[r] + myred[lane * 33 + r]) * inv;
      o1[r] = (o1[r] + myred[lane * 33 + 16 + r]) * inv;
    }
    // store: regs 4g..4g+3 are 4 consecutive d at base sub*32 + 8g + 4hw
    float* op = out + (size_t)(b * S_ + qg) * CV + h * D_;
#pragma unroll
    for (int g = 0; g < 4; g++) {
      floatx4 v0, v1;
#pragma unroll
      for (int j = 0; j < 4; j++) { v0[j] = o0[g * 4 + j]; v1[j] = o1[g * 4 + j]; }
      *(floatx4*)(op + g * 8 + hw * 4)      = v0;
      *(floatx4*)(op + 32 + g * 8 + hw * 4) = v1;
    }
  }
}

extern "C" void kernel_launch(void* const* d_in, const int* in_sizes, int n_in,
                              void* d_out, int out_size, void* d_ws, size_t ws_size,
                              hipStream_t stream) {
  const float* x   = (const float*)d_in[0];
  const float* Wqk = (const float*)d_in[1];
  const float* bqk = (const float*)d_in[2];
  const float* Wv  = (const float*)d_in[3];
  const float* bv  = (const float*)d_in[4];
  float* out = (float*)d_out;

  // Workspace (ushorts): qk [4096][2048] | V^T [2048][2048] | xbf [4096][1024]
  //                      | wtbf [3072][1024]   => ~39.8 MB total
  ushort* qkbf = (ushort*)d_ws;
  ushort* vtbf = qkbf + (size_t)(B_ * S_) * TWO_C;
  ushort* xbf  = vtbf + (size_t)TWO_C * S_;
  ushort* wtbf = xbf  + (size_t)(B_ * S_) * K_;

  dim3 blk(256);
  prep_kernel<<<dim3(1024), blk, 0, stream>>>(x, Wqk, Wv, xbf, wtbf);
  gemm_mfma<<<dim3((B_ * S_) / 128, N_ALL / 128), blk, 0, stream>>>(
      xbf, wtbf, bqk, bv, qkbf, vtbf);
  flash_attn<<<dim3(32 * 32), blk, 0, stream>>>(qkbf, vtbf, out);
}